// Round 1
// 837.148 us; speedup vs baseline: 1.0617x; 1.0617x over previous
//
#include <hip/hip_runtime.h>
#include <stdint.h>

#define BB   2
#define SS   2048
#define DD   1024
#define NH   16
#define RK   204
#define RKP  256
#define HDIM 64
#define BH   (BB*NH)

typedef __attribute__((ext_vector_type(8))) short short8;
typedef __attribute__((ext_vector_type(4))) float f32x4;
typedef unsigned short u16;
typedef unsigned int   u32;

#define NEGBIG (-1e30f)

static __device__ __forceinline__ u16 f2bf(float f) {
    union { float f; u32 u; } v; v.f = f;
    u32 u = v.u;
    return (u16)((u + 0x7fffu + ((u >> 16) & 1u)) >> 16);  // RNE
}
static __device__ __forceinline__ u32 pack2(float lo, float hi) {
    return (u32)f2bf(lo) | ((u32)f2bf(hi) << 16);
}

// ---------------- conversion kernels ----------------
__global__ void cvt_bf16_k(const float* __restrict__ in, u16* __restrict__ out, int n4) {
    int i = blockIdx.x * blockDim.x + threadIdx.x;
    if (i < n4) {
        float4 f = ((const float4*)in)[i];
        u32 lo = pack2(f.x, f.y), hi = pack2(f.z, f.w);
        ((uint2*)out)[i] = make_uint2(lo, hi);
    }
}

// U (DD x RK) fp32 -> (DD x RKP) bf16, zero pad cols [RK,RKP)
__global__ void cvt_pad_u_k(const float* __restrict__ in, u16* __restrict__ out) {
    int i = blockIdx.x * blockDim.x + threadIdx.x;
    if (i >= DD * RKP) return;
    int row = i >> 8, col = i & (RKP - 1);
    out[i] = (col < RK) ? f2bf(in[row * RK + col]) : (u16)0;
}

// vh [4096 x 1024] row-major -> vT [bh][hd][s], LDS-tiled (both global sides coalesced)
__global__ __launch_bounds__(256)
void transpose_v_k(const u16* __restrict__ vh, u16* __restrict__ vT) {
    __shared__ __align__(16) u16 T[64*72];   // [hd][s], stride 72
    const int blk = blockIdx.x;              // bh*32 + st
    const int st = blk & 31, bh = blk >> 5;
    const int b_ = bh >> 4, h = bh & (NH - 1);
    const int t = threadIdx.x;
    const int r = t >> 2, seg = t & 3;       // r: row/hd index 0..63; seg: 16-elem chunk

    // coalesced load: s = st*64 + r, hd = seg*16 .. +16
    const u16* src = vh + (size_t)(b_*SS + st*64 + r)*DD + h*HDIM + seg*16;
    __align__(16) u16 vs_[16];
    *(uint4*)(vs_ + 0) = ((const uint4*)src)[0];
    *(uint4*)(vs_ + 8) = ((const uint4*)src)[1];
    #pragma unroll
    for (int j = 0; j < 16; ++j) T[(seg*16 + j)*72 + r] = vs_[j];  // T[hd][s]
    __syncthreads();

    // coalesced store: hd = r, s-chunk = seg*16 .. +16
    u16* dst = vT + ((size_t)bh*HDIM + r)*SS + st*64 + seg*16;
    ((uint4*)dst)[0] = *(const uint4*)(T + r*72 + seg*16);
    ((uint4*)dst)[1] = *(const uint4*)(T + r*72 + seg*16 + 8);
}

// ---------------- NT GEMM: C[M x N] = A[M x K] * B[N x K]^T (+bias) ----------------
template<int A_F32, int OUT_F32, int HAS_BIAS>
__global__ __launch_bounds__(256)
void gemm_nt_k(const void* __restrict__ Ap, int lda,
               const u16* __restrict__ Bp, int ldb, int nrowsB,
               const float* __restrict__ bias,
               void* __restrict__ Cp, int ldc, int K)
{
    __shared__ __align__(16) u16 As[64*72];
    __shared__ __align__(16) u16 Bs[64*72];
    const int row0 = blockIdx.x * 64;
    const int col0 = blockIdx.y * 64;
    const int t = threadIdx.x;
    const int w = t >> 6, lane = t & 63, quad = lane >> 4, l16 = lane & 15;
    const int r = t >> 2, seg = t & 3;

    f32x4 acc0 = 0.f, acc1 = 0.f, acc2 = 0.f, acc3 = 0.f;

    for (int k0 = 0; k0 < K; k0 += 64) {
        __syncthreads();
        if (A_F32) {
            const float* ga = (const float*)Ap + (size_t)(row0 + r) * lda + k0 + seg*16;
            float4 f0 = ((const float4*)ga)[0];
            float4 f1 = ((const float4*)ga)[1];
            float4 f2 = ((const float4*)ga)[2];
            float4 f3 = ((const float4*)ga)[3];
            uint4 s0 = { pack2(f0.x,f0.y), pack2(f0.z,f0.w), pack2(f1.x,f1.y), pack2(f1.z,f1.w) };
            uint4 s1 = { pack2(f2.x,f2.y), pack2(f2.z,f2.w), pack2(f3.x,f3.y), pack2(f3.z,f3.w) };
            *(uint4*)(As + r*72 + seg*16)     = s0;
            *(uint4*)(As + r*72 + seg*16 + 8) = s1;
        } else {
            const u16* ga = (const u16*)Ap + (size_t)(row0 + r) * lda + k0 + seg*16;
            *(uint4*)(As + r*72 + seg*16)     = ((const uint4*)ga)[0];
            *(uint4*)(As + r*72 + seg*16 + 8) = ((const uint4*)ga)[1];
        }
        {
            uint4 b0 = {0,0,0,0}, b1 = {0,0,0,0};
            if (col0 + r < nrowsB) {
                const u16* gb = Bp + (size_t)(col0 + r) * ldb + k0 + seg*16;
                b0 = ((const uint4*)gb)[0];
                b1 = ((const uint4*)gb)[1];
            }
            *(uint4*)(Bs + r*72 + seg*16)     = b0;
            *(uint4*)(Bs + r*72 + seg*16 + 8) = b1;
        }
        __syncthreads();
        #pragma unroll
        for (int c = 0; c < 2; ++c) {
            short8 a = *(const short8*)(As + (w*16 + l16)*72 + c*32 + quad*8);
            short8 b0v = *(const short8*)(Bs + (0*16 + l16)*72 + c*32 + quad*8);
            acc0 = __builtin_amdgcn_mfma_f32_16x16x32_bf16(a, b0v, acc0, 0, 0, 0);
            short8 b1v = *(const short8*)(Bs + (1*16 + l16)*72 + c*32 + quad*8);
            acc1 = __builtin_amdgcn_mfma_f32_16x16x32_bf16(a, b1v, acc1, 0, 0, 0);
            short8 b2v = *(const short8*)(Bs + (2*16 + l16)*72 + c*32 + quad*8);
            acc2 = __builtin_amdgcn_mfma_f32_16x16x32_bf16(a, b2v, acc2, 0, 0, 0);
            short8 b3v = *(const short8*)(Bs + (3*16 + l16)*72 + c*32 + quad*8);
            acc3 = __builtin_amdgcn_mfma_f32_16x16x32_bf16(a, b3v, acc3, 0, 0, 0);
        }
    }

    #pragma unroll
    for (int f = 0; f < 4; ++f) {
        f32x4 a = (f==0) ? acc0 : (f==1) ? acc1 : (f==2) ? acc2 : acc3;
        int col = col0 + f*16 + l16;
        float bv = HAS_BIAS ? bias[col] : 0.f;
        #pragma unroll
        for (int rg = 0; rg < 4; ++rg) {
            int rowg = row0 + w*16 + quad*4 + rg;
            float val = a[rg] + bv;
            if (col >= nrowsB) val = 0.f;
            if (OUT_F32) ((float*)Cp)[(size_t)rowg*ldc + col] = val;
            else         ((u16*)Cp)[(size_t)rowg*ldc + col]  = f2bf(val);
        }
    }
}

// ---------------- attention pass A: per-row m,l (online softmax stats) ----------------
// Per-lane online (m,l) over this lane's key subset; single 16-lane merge at the end.
__global__ __launch_bounds__(256)
void attn_ml_k(const u16* __restrict__ qh, const u16* __restrict__ kh,
               float* __restrict__ mbuf, float* __restrict__ lbuf)
{
    __shared__ __align__(16) u16 Ks[64*72];
    const int blk = blockIdx.x;          // bh*32 + qt
    const int qt = blk & 31, bh = blk >> 5;
    const int b_ = bh >> 4, h = bh & (NH - 1);
    const int qbase = qt * 64;
    const int t = threadIdx.x, w = t >> 6, lane = t & 63, quad = lane >> 4, l16 = lane & 15;
    const int r = t >> 2, seg = t & 3;
    const float scl = 0.125f;

    const u16* qrow = qh + (size_t)(b_*SS + qbase + w*16 + l16)*DD + h*HDIM;
    short8 q0 = *(const short8*)(qrow + quad*8);
    short8 q1 = *(const short8*)(qrow + 32 + quad*8);

    float m[4], l[4];
    #pragma unroll
    for (int rg = 0; rg < 4; ++rg) { m[rg] = NEGBIG; l[rg] = 0.f; }

    for (int kt = 0; kt <= qt; ++kt) {
        int kbase = kt * 64;
        __syncthreads();
        const u16* krow = kh + (size_t)(b_*SS + kbase + r)*DD + h*HDIM + seg*16;
        uint4 kv0 = ((const uint4*)krow)[0];
        uint4 kv1 = ((const uint4*)krow)[1];
        *(uint4*)(Ks + r*72 + seg*16)     = kv0;
        *(uint4*)(Ks + r*72 + seg*16 + 8) = kv1;
        __syncthreads();

        f32x4 sa0 = 0.f, sa1 = 0.f, sa2 = 0.f, sa3 = 0.f;
        {
            short8 b0 = *(const short8*)(Ks + (0*16 + l16)*72 + quad*8);
            sa0 = __builtin_amdgcn_mfma_f32_16x16x32_bf16(q0, b0, sa0, 0,0,0);
            short8 b0b = *(const short8*)(Ks + (0*16 + l16)*72 + 32 + quad*8);
            sa0 = __builtin_amdgcn_mfma_f32_16x16x32_bf16(q1, b0b, sa0, 0,0,0);
            short8 b1 = *(const short8*)(Ks + (1*16 + l16)*72 + quad*8);
            sa1 = __builtin_amdgcn_mfma_f32_16x16x32_bf16(q0, b1, sa1, 0,0,0);
            short8 b1b = *(const short8*)(Ks + (1*16 + l16)*72 + 32 + quad*8);
            sa1 = __builtin_amdgcn_mfma_f32_16x16x32_bf16(q1, b1b, sa1, 0,0,0);
            short8 b2 = *(const short8*)(Ks + (2*16 + l16)*72 + quad*8);
            sa2 = __builtin_amdgcn_mfma_f32_16x16x32_bf16(q0, b2, sa2, 0,0,0);
            short8 b2b = *(const short8*)(Ks + (2*16 + l16)*72 + 32 + quad*8);
            sa2 = __builtin_amdgcn_mfma_f32_16x16x32_bf16(q1, b2b, sa2, 0,0,0);
            short8 b3 = *(const short8*)(Ks + (3*16 + l16)*72 + quad*8);
            sa3 = __builtin_amdgcn_mfma_f32_16x16x32_bf16(q0, b3, sa3, 0,0,0);
            short8 b3b = *(const short8*)(Ks + (3*16 + l16)*72 + 32 + quad*8);
            sa3 = __builtin_amdgcn_mfma_f32_16x16x32_bf16(q1, b3b, sa3, 0,0,0);
        }

        if (kt < qt) {
            // interior tile: all 4 keys of this lane are valid — no masks, no shuffles
            #pragma unroll
            for (int rg = 0; rg < 4; ++rg) {
                float v0 = sa0[rg]*scl, v1 = sa1[rg]*scl, v2 = sa2[rg]*scl, v3 = sa3[rg]*scl;
                float m4 = fmaxf(fmaxf(v0, v1), fmaxf(v2, v3));
                float nm = fmaxf(m[rg], m4);
                l[rg] = l[rg]*__expf(m[rg]-nm)
                      + (__expf(v0-nm)+__expf(v1-nm)) + (__expf(v2-nm)+__expf(v3-nm));
                m[rg] = nm;
            }
        } else {
            // diagonal tile: per-element causal masking (explicit zero-selects)
            int key0 = kbase + l16;
            #pragma unroll
            for (int rg = 0; rg < 4; ++rg) {
                int qg = qbase + w*16 + quad*4 + rg;
                bool c0 = (key0      <= qg), c1 = (key0 + 16 <= qg);
                bool c2 = (key0 + 32 <= qg), c3 = (key0 + 48 <= qg);
                float v0 = c0 ? sa0[rg]*scl : NEGBIG;
                float v1 = c1 ? sa1[rg]*scl : NEGBIG;
                float v2 = c2 ? sa2[rg]*scl : NEGBIG;
                float v3 = c3 ? sa3[rg]*scl : NEGBIG;
                float m4 = fmaxf(fmaxf(v0, v1), fmaxf(v2, v3));
                float nm = fmaxf(m[rg], m4);
                float e0 = c0 ? __expf(v0-nm) : 0.f;
                float e1 = c1 ? __expf(v1-nm) : 0.f;
                float e2 = c2 ? __expf(v2-nm) : 0.f;
                float e3 = c3 ? __expf(v3-nm) : 0.f;
                float corr = (m[rg] > NEGBIG) ? __expf(m[rg]-nm) : 0.f;
                l[rg] = l[rg]*corr + (e0+e1) + (e2+e3);
                m[rg] = nm;
            }
        }
    }

    // final 16-lane merge of per-lane (m,l)
    #pragma unroll
    for (int rg = 0; rg < 4; ++rg) {
        #pragma unroll
        for (int d = 1; d < 16; d <<= 1) {
            float mo = __shfl_xor(m[rg], d);
            float lo = __shfl_xor(l[rg], d);
            float nm = fmaxf(m[rg], mo);
            l[rg] = l[rg]*__expf(m[rg]-nm) + lo*__expf(mo-nm);
            m[rg] = nm;
        }
    }
    if (l16 == 0) {
        #pragma unroll
        for (int rg = 0; rg < 4; ++rg) {
            int qg = qbase + w*16 + quad*4 + rg;
            mbuf[bh*SS + qg] = m[rg];
            lbuf[bh*SS + qg] = l[rg];
        }
    }
}

// ---------------- attention pass B: attn write + O = P*V ----------------
__global__ __launch_bounds__(256)
void attn_av_k(const u16* __restrict__ qh, const u16* __restrict__ kh,
               const u16* __restrict__ vT,
               const float* __restrict__ mbuf, const float* __restrict__ lbuf,
               float* __restrict__ attn_out, u16* __restrict__ Ob)
{
    __shared__ __align__(16) u16 Ks[64*72];
    __shared__ __align__(16) u16 Vs[64*72];
    __shared__ __align__(16) u16 Ps[64*72];
    const int blk = blockIdx.x;
    const int qt = blk & 31, bh = blk >> 5;
    const int b_ = bh >> 4, h = bh & (NH - 1);
    const int qbase = qt * 64;
    const int t = threadIdx.x, w = t >> 6, lane = t & 63, quad = lane >> 4, l16 = lane & 15;
    const int r = t >> 2, seg = t & 3;
    const float scl = 0.125f;

    const u16* qrow = qh + (size_t)(b_*SS + qbase + w*16 + l16)*DD + h*HDIM;
    short8 q0 = *(const short8*)(qrow + quad*8);
    short8 q1 = *(const short8*)(qrow + 32 + quad*8);

    float mr[4], rl[4];
    #pragma unroll
    for (int rg = 0; rg < 4; ++rg) {
        int qg = qbase + w*16 + quad*4 + rg;
        mr[rg] = mbuf[bh*SS + qg];
        rl[rg] = 1.f / lbuf[bh*SS + qg];
    }
    f32x4 oa0 = 0.f, oa1 = 0.f, oa2 = 0.f, oa3 = 0.f;
    float* attn_base = attn_out + (size_t)bh * SS * SS;

    for (int kt = 0; kt <= qt; ++kt) {
        int kbase = kt * 64;
        __syncthreads();
        {
            const u16* krow = kh + (size_t)(b_*SS + kbase + r)*DD + h*HDIM + seg*16;
            *(uint4*)(Ks + r*72 + seg*16)     = ((const uint4*)krow)[0];
            *(uint4*)(Ks + r*72 + seg*16 + 8) = ((const uint4*)krow)[1];
            const u16* vrow = vT + ((size_t)(bh*HDIM + r))*SS + kbase + seg*16;
            *(uint4*)(Vs + r*72 + seg*16)     = ((const uint4*)vrow)[0];
            *(uint4*)(Vs + r*72 + seg*16 + 8) = ((const uint4*)vrow)[1];
        }
        __syncthreads();

        f32x4 sa0 = 0.f, sa1 = 0.f, sa2 = 0.f, sa3 = 0.f;
        {
            short8 b0 = *(const short8*)(Ks + (0*16 + l16)*72 + quad*8);
            sa0 = __builtin_amdgcn_mfma_f32_16x16x32_bf16(q0, b0, sa0, 0,0,0);
            short8 b0b = *(const short8*)(Ks + (0*16 + l16)*72 + 32 + quad*8);
            sa0 = __builtin_amdgcn_mfma_f32_16x16x32_bf16(q1, b0b, sa0, 0,0,0);
            short8 b1 = *(const short8*)(Ks + (1*16 + l16)*72 + quad*8);
            sa1 = __builtin_amdgcn_mfma_f32_16x16x32_bf16(q0, b1, sa1, 0,0,0);
            short8 b1b = *(const short8*)(Ks + (1*16 + l16)*72 + 32 + quad*8);
            sa1 = __builtin_amdgcn_mfma_f32_16x16x32_bf16(q1, b1b, sa1, 0,0,0);
            short8 b2 = *(const short8*)(Ks + (2*16 + l16)*72 + quad*8);
            sa2 = __builtin_amdgcn_mfma_f32_16x16x32_bf16(q0, b2, sa2, 0,0,0);
            short8 b2b = *(const short8*)(Ks + (2*16 + l16)*72 + 32 + quad*8);
            sa2 = __builtin_amdgcn_mfma_f32_16x16x32_bf16(q1, b2b, sa2, 0,0,0);
            short8 b3 = *(const short8*)(Ks + (3*16 + l16)*72 + quad*8);
            sa3 = __builtin_amdgcn_mfma_f32_16x16x32_bf16(q0, b3, sa3, 0,0,0);
            short8 b3b = *(const short8*)(Ks + (3*16 + l16)*72 + 32 + quad*8);
            sa3 = __builtin_amdgcn_mfma_f32_16x16x32_bf16(q1, b3b, sa3, 0,0,0);
        }

        // P = softmax-normalized probs; write to d_out + LDS(bf16)
        if (kt < qt) {
            // interior tile: no causal mask needed
            #pragma unroll
            for (int f = 0; f < 4; ++f) {
                f32x4 sv = (f==0) ? sa0 : (f==1) ? sa1 : (f==2) ? sa2 : sa3;
                int key = kbase + f*16 + l16;
                #pragma unroll
                for (int rg = 0; rg < 4; ++rg) {
                    int qg = qbase + w*16 + quad*4 + rg;
                    float p = __expf(sv[rg]*scl - mr[rg]) * rl[rg];
                    attn_base[(size_t)qg*SS + key] = p;
                    Ps[(w*16 + quad*4 + rg)*72 + f*16 + l16] = f2bf(p);
                }
            }
        } else {
            #pragma unroll
            for (int f = 0; f < 4; ++f) {
                f32x4 sv = (f==0) ? sa0 : (f==1) ? sa1 : (f==2) ? sa2 : sa3;
                int key = kbase + f*16 + l16;
                #pragma unroll
                for (int rg = 0; rg < 4; ++rg) {
                    int qg = qbase + w*16 + quad*4 + rg;
                    float p = (key <= qg) ? __expf(sv[rg]*scl - mr[rg]) * rl[rg] : 0.f;
                    attn_base[(size_t)qg*SS + key] = p;
                    Ps[(w*16 + quad*4 + rg)*72 + f*16 + l16] = f2bf(p);
                }
            }
        }
        // Ps rows are wave-private (wave w writes and reads rows w*16..w*16+15);
        // per-wave LDS pipe is in-order — compiler-level fence only, no barrier.
        asm volatile("" ::: "memory");

        // O += P * V
        #pragma unroll
        for (int c = 0; c < 2; ++c) {
            short8 pa = *(const short8*)(Ps + (w*16 + l16)*72 + c*32 + quad*8);
            short8 v0 = *(const short8*)(Vs + (0*16 + l16)*72 + c*32 + quad*8);
            oa0 = __builtin_amdgcn_mfma_f32_16x16x32_bf16(pa, v0, oa0, 0,0,0);
            short8 v1 = *(const short8*)(Vs + (1*16 + l16)*72 + c*32 + quad*8);
            oa1 = __builtin_amdgcn_mfma_f32_16x16x32_bf16(pa, v1, oa1, 0,0,0);
            short8 v2 = *(const short8*)(Vs + (2*16 + l16)*72 + c*32 + quad*8);
            oa2 = __builtin_amdgcn_mfma_f32_16x16x32_bf16(pa, v2, oa2, 0,0,0);
            short8 v3 = *(const short8*)(Vs + (3*16 + l16)*72 + c*32 + quad*8);
            oa3 = __builtin_amdgcn_mfma_f32_16x16x32_bf16(pa, v3, oa3, 0,0,0);
        }
    }

    // fully-masked upper tiles: explicit zeros (d_out is poisoned)
    for (int kt = qt + 1; kt < 32; ++kt) {
        int kbase = kt * 64;
        float4 z = {0.f, 0.f, 0.f, 0.f};
        float* p = attn_base + (size_t)(qbase + r)*SS + kbase + seg*16;
        ((float4*)p)[0] = z; ((float4*)p)[1] = z; ((float4*)p)[2] = z; ((float4*)p)[3] = z;
    }

    #pragma unroll
    for (int f = 0; f < 4; ++f) {
        f32x4 ov = (f==0) ? oa0 : (f==1) ? oa1 : (f==2) ? oa2 : oa3;
        #pragma unroll
        for (int rg = 0; rg < 4; ++rg) {
            int qg = qbase + w*16 + quad*4 + rg;
            Ob[(size_t)(b_*SS + qg)*DD + h*HDIM + f*16 + l16] = f2bf(ov[rg]);
        }
    }
}

// ---------------- launch ----------------
extern "C" void kernel_launch(void* const* d_in, const int* in_sizes, int n_in,
                              void* d_out, int out_size, void* d_ws, size_t ws_size,
                              hipStream_t stream)
{
    const float* xs[3] = { (const float*)d_in[0], (const float*)d_in[1], (const float*)d_in[2] };
    const float* Vw[4] = { (const float*)d_in[3], (const float*)d_in[6], (const float*)d_in[9],  (const float*)d_in[12] };
    const float* Uw[4] = { (const float*)d_in[4], (const float*)d_in[7], (const float*)d_in[10], (const float*)d_in[13] };
    const float* bw[4] = { (const float*)d_in[5], (const float*)d_in[8], (const float*)d_in[11], (const float*)d_in[14] };

    char* ws = (char*)d_ws;
    size_t off = 0;
    auto alloc = [&](size_t bytes) -> char* {
        char* p = ws + off;
        off += (bytes + 255) & ~(size_t)255;
        return p;
    };
    u16* wV[4]; for (int i = 0; i < 4; ++i) wV[i] = (u16*)alloc((size_t)RK*DD*2);
    u16* wU[4]; for (int i = 0; i < 4; ++i) wU[i] = (u16*)alloc((size_t)DD*RKP*2);
    u16* Tb  = (u16*)alloc((size_t)BB*SS*RKP*2);
    u16* hb[3]; for (int i = 0; i < 3; ++i) hb[i] = (u16*)alloc((size_t)BB*SS*DD*2);
    u16* vTb = (u16*)alloc((size_t)BB*SS*DD*2);
    float* mbuf = (float*)alloc((size_t)BH*SS*4);
    float* lbuf = (float*)alloc((size_t)BH*SS*4);
    u16* Ob  = (u16*)alloc((size_t)BB*SS*DD*2);
    (void)ws_size; (void)in_sizes; (void)n_in; (void)out_size;

    // weight conversions
    for (int i = 0; i < 4; ++i)
        cvt_bf16_k<<<(RK*DD/4 + 255)/256, 256, 0, stream>>>(Vw[i], wV[i], RK*DD/4);
    for (int i = 0; i < 4; ++i)
        cvt_pad_u_k<<<(DD*RKP + 255)/256, 256, 0, stream>>>(Uw[i], wU[i]);

    const int MROWS = BB*SS;           // 4096
    // q,k,v projections: X @ V^T -> T[4096x256 padded]; T @ U^T + b -> heads bf16
    for (int p = 0; p < 3; ++p) {
        gemm_nt_k<1,0,0><<<dim3(MROWS/64, RKP/64), 256, 0, stream>>>(
            xs[p], DD, wV[p], DD, RK, nullptr, Tb, RKP, DD);
        gemm_nt_k<0,0,1><<<dim3(MROWS/64, DD/64), 256, 0, stream>>>(
            Tb, RKP, wU[p], RKP, DD, bw[p], hb[p], DD, RKP);
    }
    transpose_v_k<<<BH*32, 256, 0, stream>>>(hb[2], vTb);

    float* attn_out = (float*)d_out + (size_t)BB*SS*DD;
    attn_ml_k<<<BH*32, 256, 0, stream>>>(hb[0], hb[1], mbuf, lbuf);
    attn_av_k<<<BH*32, 256, 0, stream>>>(hb[0], hb[1], vTb, mbuf, lbuf, attn_out, Ob);

    // output projection: O @ Vo^T -> T; T @ Uo^T + bo -> d_out (fp32)
    gemm_nt_k<0,0,0><<<dim3(MROWS/64, RKP/64), 256, 0, stream>>>(
        Ob, DD, wV[3], DD, RK, nullptr, Tb, RKP, DD);
    gemm_nt_k<0,1,1><<<dim3(MROWS/64, DD/64), 256, 0, stream>>>(
        Tb, RKP, wU[3], RKP, DD, bw[3], d_out, DD, RKP);
}